// Round 10
// baseline (281.584 us; speedup 1.0000x reference)
//
#include <hip/hip_runtime.h>
#include <stdint.h>

#define BATCH 128
#define NN 512
#define BINS 100
#define WORDS 8    // 512 bits / 64; natural order: bit b of word m = column 64m+b
#define WPAD 9     // +1 u64 pad -> benign LDS bank aliasing
#define ECAP 6144  // upper-tri edge capacity; expected ~2615, huge margin
#define NT 512     // 8 waves/block; 63.9KB LDS -> 2 blocks/CU for read/compute overlap

// spread 16 bits to stride-4 positions (bit i -> bit 4i)
__device__ __forceinline__ unsigned long long spread4(unsigned long long x) {
    x = (x | (x << 24)) & 0x000000ff000000ffull;
    x = (x | (x << 12)) & 0x000f000f000f000full;
    x = (x | (x <<  6)) & 0x0303030303030303ull;
    x = (x | (x <<  3)) & 0x1111111111111111ull;
    return x;
}

// One block per graph, 512 threads, 2 blocks/CU: one block's post-barrier
// compute (transpose/edges/triangles/hist) overlaps the other block's
// upper-triangle read stream, keeping the CU read pipe busy (the measured
// limiter is ~2.6 TB/s of touched lines; compute was a serial ~22us tail).
// Phase logic identical to R9 (verified absmax 0).
__global__ __launch_bounds__(NT) void k_cluster_hist(
    const float* __restrict__ adj1, const float* __restrict__ adj2,
    float* __restrict__ hist /* [2*BATCH][BINS] */)
{
    __shared__ unsigned long long bits[NN][WPAD];   // 36,864 B
    __shared__ unsigned int edges[ECAP];            // 24,576 B
    __shared__ int tri2[NN];                        //  2,048 B
    __shared__ int histI[BINS];
    __shared__ int ecnt;

    const int gb = blockIdx.x;  // 0..255
    const float* __restrict__ gp =
        (gb < BATCH ? adj1 : adj2) + (size_t)(gb & (BATCH - 1)) * NN * NN;

    const int tid  = threadIdx.x;
    const int lane = tid & 63;
    const int wave = tid >> 6;  // 0..7

    if (tid < BINS) histI[tid] = 0;
    for (int i = tid; i < NN; i += NT) tri2[i] = 0;
    if (tid == 0) ecnt = 0;

    // ---- Phase 1: upper-triangle read + natural-order pack.
    for (int r = wave; r < NN; r += 8) {
        const int br = r >> 6;       // diagonal 64-col block
        const int nb = 8 - br;       // words to read
        const int c0 = br << 6;
        const int rr = r & 63;
        const int Lmin = (rr < 3) ? 0 : ((rr + 1) >> 2);  // skip wholly-below-diag 16B groups
        float4 v = make_float4(0.f, 0.f, 0.f, 0.f);
        if (lane < 16 * nb && (lane >= 16 || lane >= Lmin))
            v = *(const float4*)(gp + (size_t)r * NN + c0 + 4 * lane);
        unsigned long long b0 = __ballot(v.x != 0.0f);
        unsigned long long b1 = __ballot(v.y != 0.0f);
        unsigned long long b2 = __ballot(v.z != 0.0f);
        unsigned long long b3 = __ballot(v.w != 0.0f);
        if (lane < nb) {
            const int sh = 16 * lane;
            unsigned long long w =
                (spread4((b0 >> sh) & 0xFFFFull) << 0) |
                (spread4((b1 >> sh) & 0xFFFFull) << 1) |
                (spread4((b2 >> sh) & 0xFFFFull) << 2) |
                (spread4((b3 >> sh) & 0xFFFFull) << 3);
            bits[r][br + lane] = w;
        }
    }
    __syncthreads();

    // ---- Phase 1b: lower triangle by symmetry (64x64 bit transposes).
    // Items 0..27: off-diagonal (bi,bj), bj<bi; 28..35: diagonal x | x^T.
    for (int p = wave; p < 36; p += 8) {
        int bi, bj;
        if (p < 28) {
            bi = 1;
            while (bi * (bi + 1) / 2 <= p) ++bi;
            bj = p - bi * (bi - 1) / 2;
        } else {
            bi = p - 28; bj = bi;
        }
        unsigned long long x = bits[(bj << 6) + lane][bi];
        unsigned long long t = x;
        const unsigned long long M[6] = {
            0x5555555555555555ull, 0x3333333333333333ull,
            0x0f0f0f0f0f0f0f0full, 0x00ff00ff00ff00ffull,
            0x0000ffff0000ffffull, 0x00000000ffffffffull };
        #pragma unroll
        for (int s = 0; s < 6; ++s) {
            const int k = 1 << s;
            unsigned long long y = __shfl_xor((long long)t, k, 64);
            if ((lane & k) == 0) t = (t &  M[s]) | ((y &  M[s]) << k);
            else                 t = (t & ~M[s]) | ((y & ~M[s]) >> k);
        }
        if (p < 28) bits[(bi << 6) + lane][bj] = t;
        else        bits[(bi << 6) + lane][bi] = x | t;
    }
    __syncthreads();

    // ---- Phase 2a: upper-tri edge list (j > r); j = 64m + L.
    for (int p = tid; p < NN * WORDS; p += NT) {
        int r = p >> 3;
        int m = p & 7;
        unsigned long long w = bits[r][m];
        int base = m << 6;
        int sh = r - base + 1;
        unsigned long long wm =
            (sh <= 0) ? w : (sh >= 64 ? 0ull : (w & (~0ull << sh)));
        int cnt = __popcll(wm);

        int x = cnt;
        #pragma unroll
        for (int off = 1; off < 64; off <<= 1) {
            int y = __shfl_up(x, off, 64);
            if (lane >= off) x += y;
        }
        int excl = x - cnt;
        int bs = 0;
        if (lane == 63) bs = atomicAdd(&ecnt, x);
        bs = __shfl(bs, 63, 64);

        int idx = bs + excl;
        while (wm) {
            int L = __builtin_ctzll(wm);
            wm &= wm - 1;
            int j = base + L;
            if (idx < ECAP) edges[idx] = ((unsigned)r << 10) | (unsigned)j;
            ++idx;
        }
    }
    __syncthreads();

    // ---- Phase 2b: edge-parallel intersection counts.
    const int ne = ecnt < ECAP ? ecnt : ECAP;
    for (int e = tid; e < ne; e += NT) {
        unsigned ed = edges[e];
        int i = ed >> 10;
        int j = ed & 1023;
        int acc = 0;
        #pragma unroll
        for (int w = 0; w < WORDS; ++w)
            acc += __popcll(bits[i][w] & bits[j][w]);
        atomicAdd(&tri2[i], acc);
        atomicAdd(&tri2[j], acc);
    }
    __syncthreads();

    // ---- Phase 2c: clustering coeff + histogram.
    for (int r = tid; r < NN; r += NT) {
        int deg = 0;
        #pragma unroll
        for (int w = 0; w < WORDS; ++w) deg += __popcll(bits[r][w]);
        float t2    = (float)tri2[r];
        float degf  = (float)deg;
        float denom = degf * (degf - 1.0f);
        float c = denom > 0.0f ? t2 / denom : 0.0f;  // exact int/int in fp32
        int idx = (int)(c * 100.0f);                  // trunc == astype(int32)
        idx = idx < 0 ? 0 : (idx > BINS - 1 ? BINS - 1 : idx);
        atomicAdd(&histI[idx], 1);
    }
    __syncthreads();

    if (tid < BINS) hist[(size_t)gb * BINS + tid] = (float)histI[tid];
}

// ---------------- MMD kernels ----------------------------------------------
__global__ __launch_bounds__(256) void k_mmd_partial(
    const float* __restrict__ hist, float* __restrict__ partials)
{
    int p = blockIdx.x * 256 + threadIdx.x;
    int t   = p >> 14;          // 0:XX 1:YY 2:XY
    int rem = p & 16383;
    int i = rem >> 7;
    int j = rem & 127;
    const float4* x4;
    const float4* y4;
    float w;
    if (t == 0)      { x4 = (const float4*)(hist + (size_t)i * BINS);           y4 = (const float4*)(hist + (size_t)j * BINS);           w =  1.0f; }
    else if (t == 1) { x4 = (const float4*)(hist + (size_t)(BATCH + i) * BINS); y4 = (const float4*)(hist + (size_t)(BATCH + j) * BINS); w =  1.0f; }
    else             { x4 = (const float4*)(hist + (size_t)i * BINS);           y4 = (const float4*)(hist + (size_t)(BATCH + j) * BINS); w = -2.0f; }
    float sq = 0.0f;
    #pragma unroll
    for (int k = 0; k < BINS / 4; ++k) {
        float4 a = x4[k];
        float4 b = y4[k];
        float d0 = a.x - b.x, d1 = a.y - b.y, d2 = a.z - b.z, d3 = a.w - b.w;
        sq += d0 * d0 + d1 * d1 + d2 * d2 + d3 * d3;
    }
    float local = w * expf(-0.5f * sq);  // sigma=1

    __shared__ float red[256];
    red[threadIdx.x] = local;
    __syncthreads();
    for (int s = 128; s >= 1; s >>= 1) {
        if (threadIdx.x < s) red[threadIdx.x] += red[threadIdx.x + s];
        __syncthreads();
    }
    if (threadIdx.x == 0) partials[blockIdx.x] = red[0];
}

__global__ __launch_bounds__(64) void k_mmd_final(
    const float* __restrict__ partials, float* __restrict__ out, int nparts)
{
    int lane = threadIdx.x;
    float v = 0.0f;
    for (int p = lane; p < nparts; p += 64) v += partials[p];
    #pragma unroll
    for (int off = 32; off >= 1; off >>= 1) v += __shfl_xor(v, off, 64);
    if (lane == 0) out[0] = v * (1.0f / (float)(BATCH * BATCH));
}

extern "C" void kernel_launch(void* const* d_in, const int* in_sizes, int n_in,
                              void* d_out, int out_size, void* d_ws, size_t ws_size,
                              hipStream_t stream) {
    const float* a1 = (const float*)d_in[0];
    const float* a2 = (const float*)d_in[1];
    float* out = (float*)d_out;

    const size_t hist_bytes = (size_t)2 * BATCH * BINS * 4;  // 102.4 KB
    float* hist     = (float*)d_ws;
    float* partials = (float*)((char*)d_ws + hist_bytes);

    hipLaunchKernelGGL(k_cluster_hist, dim3(2 * BATCH), dim3(NT), 0, stream,
                       a1, a2, hist);
    hipLaunchKernelGGL(k_mmd_partial, dim3(192), dim3(256), 0, stream,
                       hist, partials);
    hipLaunchKernelGGL(k_mmd_final, dim3(1), dim3(64), 0, stream,
                       partials, out, 192);
}

// Round 11
// 255.692 us; speedup vs baseline: 1.1013x; 1.1013x over previous
//
#include <hip/hip_runtime.h>
#include <stdint.h>

#define BATCH 128
#define NN 512
#define BINS 100
#define WORDS 8    // 512 bits / 64; natural order: bit b of word m = column 64m+b
#define WPAD 9     // +1 u64 pad -> benign LDS bank aliasing
#define ECAP 6144  // upper-tri edge capacity; expected ~2615, huge margin

// spread 16 bits to stride-4 positions (bit i -> bit 4i)
__device__ __forceinline__ unsigned long long spread4(unsigned long long x) {
    x = (x | (x << 24)) & 0x000000ff000000ffull;
    x = (x | (x << 12)) & 0x000f000f000f000full;
    x = (x | (x <<  6)) & 0x0303030303030303ull;
    x = (x | (x <<  3)) & 0x1111111111111111ull;
    return x;
}

// R9 configuration (best measured: 256.1 us total, absmax 0).
// One block per graph, 1024 threads. Phase 1 reads the upper triangle with
// float4 (time scales with cache lines touched; ~30cyc/line/CU pin measured
// across 5 staging structures), with a diagonal-word lane mask skipping 16B
// groups wholly below the diagonal. Phase 1b rebuilds the lower triangle:
// 28 off-diagonal 64x64 bit transposes + 8 diagonal OR-transposes (A
// symmetric -> x | x^T exact). Phase 2a: scan-aggregated upper-tri edge
// list; 2b: edge-parallel AND+popcount; 2c: clustering coeff + histogram.
__global__ __launch_bounds__(1024) void k_cluster_hist(
    const float* __restrict__ adj1, const float* __restrict__ adj2,
    float* __restrict__ hist /* [2*BATCH][BINS] */)
{
    __shared__ unsigned long long bits[NN][WPAD];   // 36,864 B
    __shared__ unsigned int edges[ECAP];            // 24,576 B
    __shared__ int tri2[NN];                        //  2,048 B
    __shared__ int histI[BINS];
    __shared__ int ecnt;

    const int gb = blockIdx.x;  // 0..255
    const float* __restrict__ gp =
        (gb < BATCH ? adj1 : adj2) + (size_t)(gb & (BATCH - 1)) * NN * NN;

    const int tid  = threadIdx.x;
    const int lane = tid & 63;
    const int wave = tid >> 6;  // 0..15

    if (tid < BINS) histI[tid] = 0;
    if (tid < NN)   tri2[tid]  = 0;
    if (tid == 0)   ecnt = 0;

    // ---- Phase 1: upper-triangle read + natural-order pack.
    for (int r = wave; r < NN; r += 16) {
        const int br = r >> 6;       // diagonal 64-col block
        const int nb = 8 - br;       // words to read
        const int c0 = br << 6;
        const int rr = r & 63;
        // lanes 0..15 cover the diagonal word; skip lanes with all 4 cols <= r
        const int Lmin = (rr < 3) ? 0 : ((rr + 1) >> 2);
        float4 v = make_float4(0.f, 0.f, 0.f, 0.f);
        if (lane < 16 * nb && (lane >= 16 || lane >= Lmin))
            v = *(const float4*)(gp + (size_t)r * NN + c0 + 4 * lane);
        unsigned long long b0 = __ballot(v.x != 0.0f);
        unsigned long long b1 = __ballot(v.y != 0.0f);
        unsigned long long b2 = __ballot(v.z != 0.0f);
        unsigned long long b3 = __ballot(v.w != 0.0f);
        // lane d < nb assembles natural word m = br + d from span word s = d
        if (lane < nb) {
            const int sh = 16 * lane;
            unsigned long long w =
                (spread4((b0 >> sh) & 0xFFFFull) << 0) |
                (spread4((b1 >> sh) & 0xFFFFull) << 1) |
                (spread4((b2 >> sh) & 0xFFFFull) << 2) |
                (spread4((b3 >> sh) & 0xFFFFull) << 3);
            bits[r][br + lane] = w;
        }
    }
    __syncthreads();

    // ---- Phase 1b: fill lower triangle by symmetry (64x64 bit transposes).
    // Items 0..27: off-diagonal pairs (bi,bj), bj<bi. Items 28..35: diagonal
    // blocks bi=bj=p-28, completed as x | transpose(x).
    for (int p = wave; p < 36; p += 16) {
        int bi, bj;
        if (p < 28) {
            bi = 1;
            while (bi * (bi + 1) / 2 <= p) ++bi;
            bj = p - bi * (bi - 1) / 2;
        } else {
            bi = p - 28; bj = bi;
        }
        unsigned long long x = bits[(bj << 6) + lane][bi];
        unsigned long long t = x;
        const unsigned long long M[6] = {
            0x5555555555555555ull, 0x3333333333333333ull,
            0x0f0f0f0f0f0f0f0full, 0x00ff00ff00ff00ffull,
            0x0000ffff0000ffffull, 0x00000000ffffffffull };
        #pragma unroll
        for (int s = 0; s < 6; ++s) {
            const int k = 1 << s;
            unsigned long long y = __shfl_xor((long long)t, k, 64);
            if ((lane & k) == 0) t = (t &  M[s]) | ((y &  M[s]) << k);
            else                 t = (t & ~M[s]) | ((y & ~M[s]) >> k);
        }
        if (p < 28) bits[(bi << 6) + lane][bj] = t;       // pure transpose
        else        bits[(bi << 6) + lane][bi] = x | t;   // symmetric completion
    }
    __syncthreads();

    // ---- Phase 2a: upper-tri edge list (j > r); j = 64m + L.
    for (int p = tid; p < NN * WORDS; p += 1024) {
        int r = p >> 3;
        int m = p & 7;
        unsigned long long w = bits[r][m];
        int base = m << 6;
        int sh = r - base + 1;  // keep bits L with base+L > r
        unsigned long long wm =
            (sh <= 0) ? w : (sh >= 64 ? 0ull : (w & (~0ull << sh)));
        int cnt = __popcll(wm);

        int x = cnt;
        #pragma unroll
        for (int off = 1; off < 64; off <<= 1) {
            int y = __shfl_up(x, off, 64);
            if (lane >= off) x += y;
        }
        int excl = x - cnt;
        int bs = 0;
        if (lane == 63) bs = atomicAdd(&ecnt, x);
        bs = __shfl(bs, 63, 64);

        int idx = bs + excl;
        while (wm) {
            int L = __builtin_ctzll(wm);
            wm &= wm - 1;
            int j = base + L;
            if (idx < ECAP) edges[idx] = ((unsigned)r << 10) | (unsigned)j;
            ++idx;
        }
    }
    __syncthreads();

    // ---- Phase 2b: edge-parallel intersection counts.
    const int ne = ecnt < ECAP ? ecnt : ECAP;
    for (int e = tid; e < ne; e += 1024) {
        unsigned ed = edges[e];
        int i = ed >> 10;
        int j = ed & 1023;
        int acc = 0;
        #pragma unroll
        for (int w = 0; w < WORDS; ++w)
            acc += __popcll(bits[i][w] & bits[j][w]);
        atomicAdd(&tri2[i], acc);
        atomicAdd(&tri2[j], acc);
    }
    __syncthreads();

    // ---- Phase 2c: clustering coeff + histogram.
    if (tid < NN) {
        int deg = 0;
        #pragma unroll
        for (int w = 0; w < WORDS; ++w) deg += __popcll(bits[tid][w]);
        float t2    = (float)tri2[tid];
        float degf  = (float)deg;
        float denom = degf * (degf - 1.0f);
        float c = denom > 0.0f ? t2 / denom : 0.0f;  // exact int/int in fp32
        int idx = (int)(c * 100.0f);                  // trunc == astype(int32)
        idx = idx < 0 ? 0 : (idx > BINS - 1 ? BINS - 1 : idx);
        atomicAdd(&histI[idx], 1);
    }
    __syncthreads();

    if (tid < BINS) hist[(size_t)gb * BINS + tid] = (float)histI[tid];
}

// ---------------- MMD kernels ----------------------------------------------
__global__ __launch_bounds__(256) void k_mmd_partial(
    const float* __restrict__ hist, float* __restrict__ partials)
{
    int p = blockIdx.x * 256 + threadIdx.x;
    int t   = p >> 14;          // 0:XX 1:YY 2:XY
    int rem = p & 16383;
    int i = rem >> 7;
    int j = rem & 127;
    const float4* x4;
    const float4* y4;
    float w;
    if (t == 0)      { x4 = (const float4*)(hist + (size_t)i * BINS);           y4 = (const float4*)(hist + (size_t)j * BINS);           w =  1.0f; }
    else if (t == 1) { x4 = (const float4*)(hist + (size_t)(BATCH + i) * BINS); y4 = (const float4*)(hist + (size_t)(BATCH + j) * BINS); w =  1.0f; }
    else             { x4 = (const float4*)(hist + (size_t)i * BINS);           y4 = (const float4*)(hist + (size_t)(BATCH + j) * BINS); w = -2.0f; }
    float sq = 0.0f;
    #pragma unroll
    for (int k = 0; k < BINS / 4; ++k) {
        float4 a = x4[k];
        float4 b = y4[k];
        float d0 = a.x - b.x, d1 = a.y - b.y, d2 = a.z - b.z, d3 = a.w - b.w;
        sq += d0 * d0 + d1 * d1 + d2 * d2 + d3 * d3;
    }
    float local = w * expf(-0.5f * sq);  // sigma=1

    __shared__ float red[256];
    red[threadIdx.x] = local;
    __syncthreads();
    for (int s = 128; s >= 1; s >>= 1) {
        if (threadIdx.x < s) red[threadIdx.x] += red[threadIdx.x + s];
        __syncthreads();
    }
    if (threadIdx.x == 0) partials[blockIdx.x] = red[0];
}

__global__ __launch_bounds__(64) void k_mmd_final(
    const float* __restrict__ partials, float* __restrict__ out, int nparts)
{
    int lane = threadIdx.x;
    float v = 0.0f;
    for (int p = lane; p < nparts; p += 64) v += partials[p];
    #pragma unroll
    for (int off = 32; off >= 1; off >>= 1) v += __shfl_xor(v, off, 64);
    if (lane == 0) out[0] = v * (1.0f / (float)(BATCH * BATCH));
}

extern "C" void kernel_launch(void* const* d_in, const int* in_sizes, int n_in,
                              void* d_out, int out_size, void* d_ws, size_t ws_size,
                              hipStream_t stream) {
    const float* a1 = (const float*)d_in[0];
    const float* a2 = (const float*)d_in[1];
    float* out = (float*)d_out;

    const size_t hist_bytes = (size_t)2 * BATCH * BINS * 4;  // 102.4 KB
    float* hist     = (float*)d_ws;
    float* partials = (float*)((char*)d_ws + hist_bytes);

    hipLaunchKernelGGL(k_cluster_hist, dim3(2 * BATCH), dim3(1024), 0, stream,
                       a1, a2, hist);
    hipLaunchKernelGGL(k_mmd_partial, dim3(192), dim3(256), 0, stream,
                       hist, partials);
    hipLaunchKernelGGL(k_mmd_final, dim3(1), dim3(64), 0, stream,
                       partials, out, 192);
}